// Round 2
// baseline (852.482 us; speedup 1.0000x reference)
//
#include <hip/hip_runtime.h>
#include <cstdint>
#include <cstddef>

#define TSTEPS 1024
#define NB 256
#define NI 128
#define NH 128
#define NC 18
#define CH 32
#define NCHUNK (TSTEPS/CH)   // 32
#define XGS 516              // xgp row stride in f32 (rows 16B-aligned, quads split across banks)

typedef _Float16 f16x8 __attribute__((ext_vector_type(8)));
typedef float    f32x4 __attribute__((ext_vector_type(4)));
typedef _Float16 half2_t __attribute__((ext_vector_type(2)));

__device__ __forceinline__ half2_t as_h2(uint32_t v){
  union { uint32_t u; half2_t h; } cv; cv.u = v; return cv.h;
}
__device__ __forceinline__ uint32_t pku(float a, float b){
  union { half2_t h; uint32_t u; } cv; cv.h.x=(_Float16)a; cv.h.y=(_Float16)b; return cv.u;
}
__device__ __forceinline__ float dot2f(half2_t a, half2_t b, float c){
#if __has_builtin(__builtin_amdgcn_fdot2)
  return __builtin_amdgcn_fdot2(a, b, c, false);
#else
  return c + (float)a.x*(float)b.x + (float)a.y*(float)b.y;
#endif
}
__device__ __forceinline__ float fast_rcp(float x){
#if __has_builtin(__builtin_amdgcn_rcpf)
  return __builtin_amdgcn_rcpf(x);
#else
  return 1.f / x;
#endif
}
// clamp-free sigmoid: exp(-v) -> inf/0 saturates rcp to 0/1; no NaN for finite v
__device__ __forceinline__ float sigm(float v){
  return fast_rcp(1.f + __expf(-v));
}
// tanh(v) = 1 - 2/(1+e^{2v}); saturates to +-1 at +-inf
__device__ __forceinline__ float tanhx(float v){
  float r = fast_rcp(1.f + __expf(2.f*v));
  return __builtin_fmaf(-2.f, r, 1.f);
}
// 8 consecutive f32 -> f16x8 (one MFMA operand row-slice)
__device__ __forceinline__ f16x8 ldrow_f16(const float* base){
  float4 f0 = ((const float4*)base)[0];
  float4 f1 = ((const float4*)base)[1];
  f16x8 r;
  r[0]=(_Float16)f0.x; r[1]=(_Float16)f0.y; r[2]=(_Float16)f0.z; r[3]=(_Float16)f0.w;
  r[4]=(_Float16)f1.x; r[5]=(_Float16)f1.y; r[6]=(_Float16)f1.z; r[7]=(_Float16)f1.w;
  return r;
}
// lgkm-only workgroup barrier: all in-loop cross-wave deps are LDS; global
// prefetch loads and out-stores stay in flight across it.
__device__ __forceinline__ void barrier_lds(){
  asm volatile("s_waitcnt lgkmcnt(0)" ::: "memory");
  __builtin_amdgcn_s_barrier();
}

// x-GEMM slice for next chunk: compile-time gate-type Q, runtime mt (addr only).
#define X_SLICE(Q) do {                                                          \
    const int mt_ = s_ & 1;                                                      \
    f16x8 xa0 = *(const f16x8*)&xs[mt_*16+n][0*32+quad*8];                       \
    f16x8 xa1 = *(const f16x8*)&xs[mt_*16+n][1*32+quad*8];                       \
    f16x8 xa2 = *(const f16x8*)&xs[mt_*16+n][2*32+quad*8];                       \
    f16x8 xa3 = *(const f16x8*)&xs[mt_*16+n][3*32+quad*8];                       \
    f32x4 acc_ = { biasq[Q], biasq[Q], biasq[Q], biasq[Q] };                     \
    acc_ = __builtin_amdgcn_mfma_f32_16x16x32_f16(xa0, wih[Q][0], acc_, 0,0,0);  \
    acc_ = __builtin_amdgcn_mfma_f32_16x16x32_f16(xa1, wih[Q][1], acc_, 0,0,0);  \
    acc_ = __builtin_amdgcn_mfma_f32_16x16x32_f16(xa2, wih[Q][2], acc_, 0,0,0);  \
    acc_ = __builtin_amdgcn_mfma_f32_16x16x32_f16(xa3, wih[Q][3], acc_, 0,0,0);  \
    xgn[mt_*16+quad*4+0][cellw4+(Q)] = acc_[0];                                  \
    xgn[mt_*16+quad*4+1][cellw4+(Q)] = acc_[1];                                  \
    xgn[mt_*16+quad*4+2][cellw4+(Q)] = acc_[2];                                  \
    xgn[mt_*16+quad*4+3][cellw4+(Q)] = acc_[3];                                  \
  } while(0)

// Head slice for chunk (ckh-1): compile-time jj = J (register accumulators),
// runtime q (LDS addresses only).
#define HEAD_SLICE(J, ACC, FJ) do {                                              \
    if ((J)==0 || jb+16 < NC){                                                   \
      const int j_ = jb + 16*(J);                                                \
      const uint4* hb_ = (const uint4*)&hist[((ckh-1)*CH + hr) & 63][0];         \
      const uint2* fw_ = (const uint2*)&fcw[j_][0];                              \
      uint4 v0=hb_[qh], v1=hb_[4+qh], v2=hb_[8+qh], v3=hb_[12+qh];               \
      uint2 f0a=fw_[2*qh],    f0b=fw_[2*qh+1];                                   \
      uint2 f1a=fw_[8+2*qh],  f1b=fw_[8+2*qh+1];                                 \
      uint2 f2a=fw_[16+2*qh], f2b=fw_[16+2*qh+1];                                \
      uint2 f3a=fw_[24+2*qh], f3b=fw_[24+2*qh+1];                                \
      ACC[0]=dot2f(as_h2(f0a.x),as_h2(v0.x),ACC[0]);                             \
      ACC[1]=dot2f(as_h2(f1a.x),as_h2(v1.x),ACC[1]);                             \
      ACC[2]=dot2f(as_h2(f2a.x),as_h2(v2.x),ACC[2]);                             \
      ACC[3]=dot2f(as_h2(f3a.x),as_h2(v3.x),ACC[3]);                             \
      ACC[0]=dot2f(as_h2(f0a.y),as_h2(v0.y),ACC[0]);                             \
      ACC[1]=dot2f(as_h2(f1a.y),as_h2(v1.y),ACC[1]);                             \
      ACC[2]=dot2f(as_h2(f2a.y),as_h2(v2.y),ACC[2]);                             \
      ACC[3]=dot2f(as_h2(f3a.y),as_h2(v3.y),ACC[3]);                             \
      ACC[0]=dot2f(as_h2(f0b.x),as_h2(v0.z),ACC[0]);                             \
      ACC[1]=dot2f(as_h2(f1b.x),as_h2(v1.z),ACC[1]);                             \
      ACC[2]=dot2f(as_h2(f2b.x),as_h2(v2.z),ACC[2]);                             \
      ACC[3]=dot2f(as_h2(f3b.x),as_h2(v3.z),ACC[3]);                             \
      ACC[0]=dot2f(as_h2(f0b.y),as_h2(v0.w),ACC[0]);                             \
      ACC[1]=dot2f(as_h2(f1b.y),as_h2(v1.w),ACC[1]);                             \
      ACC[2]=dot2f(as_h2(f2b.y),as_h2(v2.w),ACC[2]);                             \
      ACC[3]=dot2f(as_h2(f3b.y),as_h2(v3.w),ACC[3]);                             \
      if (qh == 3){                                                              \
        out[(size_t)((ckh-1)*CH + hr)*NB*NC + (size_t)b*NC + j_] =               \
            (ACC[0]+ACC[1]) + (ACC[2]+ACC[3]) + (FJ);                            \
        ACC[0]=0.f; ACC[1]=0.f; ACC[2]=0.f; ACC[3]=0.f;                          \
      }                                                                          \
    }                                                                            \
  } while(0)

// One block per batch row, 512 threads (8 waves).
// Wave w, gate-type q, cell = w*16 + n. Recurrent step = 16 MFMA/wave (M=1 of 16
// used; afr unmasked -> all A rows are replicas of h, harmless).
// hist = 64-row linear ring over global step index; head of chunk ck-1 and
// x-GEMM of chunk ck+1 interleave as slices inside chunk ck's step loop.
__global__ __launch_bounds__(512, 2) void lstm_mfma(
    const float* __restrict__ x,      // [T,B,I]
    const float* __restrict__ h0,     // [B,H]
    const float* __restrict__ c0,     // [B,H]
    const float* __restrict__ Wih,    // [4H,I]
    const float* __restrict__ Whh,    // [4H,H]
    const float* __restrict__ bih,    // [4H]
    const float* __restrict__ bhh,    // [4H]
    const float* __restrict__ fcW,    // [18,H]
    const float* __restrict__ fcb,    // [18]
    float* __restrict__ out,          // [T,B,18]
    float* __restrict__ hT,           // [B,H]
    float* __restrict__ cT)           // [B,H]
{
  const int b    = blockIdx.x;
  const int tid  = threadIdx.x;
  const int w    = tid >> 6;      // wave 0..7
  const int l    = tid & 63;
  const int n    = l & 15;        // tile col
  const int quad = l >> 4;        // k-chunk within frag
  const int cellw4 = (w*16 + n)*4;

  __shared__ __align__(16) _Float16 xs[CH][136];       // x chunk f16 (+pad)    8704 B
  __shared__ __align__(16) float    xgp[2][CH][XGS];   // x-gates dbuf        132096 B
  __shared__ __align__(16) _Float16 hist[64][128];     // h linear ring        16384 B
  __shared__ __align__(16) uint32_t fcw[NC][66];       // head W f16 (+pad)     4752 B
                                                       // total              161936 B
  // ---- persistent weight B-frags: Whh + Wih, [q][kt], 128 VGPRs ----
  f16x8 whh[4][4], wih[4][4];
#pragma unroll
  for (int q = 0; q < 4; ++q){
    const int row = q*128 + w*16 + n;
#pragma unroll
    for (int kt = 0; kt < 4; ++kt){
      whh[q][kt] = ldrow_f16(Whh + (size_t)row*NH + kt*32 + quad*8);
      wih[q][kt] = ldrow_f16(Wih + (size_t)row*NI + kt*32 + quad*8);
    }
  }
  float biasq[4];
#pragma unroll
  for (int q = 0; q < 4; ++q){
    const int g = q*128 + w*16 + n;
    biasq[q] = bih[g] + bhh[g];
  }
  float cst = c0[(size_t)b*NH + w*16 + n];   // valid lanes l<16

  if (tid < 128) hist[63][tid] = (_Float16)h0[(size_t)b*NH + tid];  // ring seed
#pragma unroll
  for (int r = 0; r < 3; ++r){
    int idx = tid + 512*r;                   // 18*64 = 1152 targets
    if (idx < NC*64){
      int j = idx >> 6, k = idx & 63;
      float2 f = ((const float2*)(fcW + (size_t)j*NH))[k];
      fcw[j][k] = pku(f.x, f.y);
    }
  }

  // ---- head constants & state ----
  const int jb = tid & 15;
  const int hr = tid >> 4;                   // head row 0..31
  const float fj0 = fcb[jb];
  const float fj1 = (jb + 16 < NC) ? fcb[jb+16] : 0.f;
  f32x4 accH0 = {0.f,0.f,0.f,0.f}, accH1 = {0.f,0.f,0.f,0.f};

  // ---- prefetch x chunk 0 ----
  const int ttA = tid >> 5;                  // 0..15
  const int ttB = ttA + 16;                  // 16..31
  const int k4  = tid & 31;
  float4 xpA = ((const float4*)(x + ((size_t)ttA*NB + b)*NI))[k4];
  float4 xpB = ((const float4*)(x + ((size_t)ttB*NB + b)*NI))[k4];
  __syncthreads();

  // ---- stage xs(0) ----
  {
    union { _Float16 h[4]; uint2 u2; } pa, pb;
    pa.h[0]=(_Float16)xpA.x; pa.h[1]=(_Float16)xpA.y;
    pa.h[2]=(_Float16)xpA.z; pa.h[3]=(_Float16)xpA.w;
    *(uint2*)&xs[ttA][4*k4] = pa.u2;
    pb.h[0]=(_Float16)xpB.x; pb.h[1]=(_Float16)xpB.y;
    pb.h[2]=(_Float16)xpB.z; pb.h[3]=(_Float16)xpB.w;
    *(uint2*)&xs[ttB][4*k4] = pb.u2;
  }
  barrier_lds();

  // ---- full x-GEMM(0) -> xgp[0] ----
  {
    f16x8 xa[2][4];
#pragma unroll
    for (int mt = 0; mt < 2; ++mt)
#pragma unroll
      for (int kt = 0; kt < 4; ++kt)
        xa[mt][kt] = *(const f16x8*)&xs[mt*16 + n][kt*32 + quad*8];
#pragma unroll
    for (int q = 0; q < 4; ++q){
#pragma unroll
      for (int mt = 0; mt < 2; ++mt){
        f32x4 acc = { biasq[q], biasq[q], biasq[q], biasq[q] };
#pragma unroll
        for (int kt = 0; kt < 4; ++kt)
          acc = __builtin_amdgcn_mfma_f32_16x16x32_f16(xa[mt][kt], wih[q][kt], acc, 0, 0, 0);
#pragma unroll
        for (int r = 0; r < 4; ++r)
          xgp[0][mt*16 + quad*4 + r][cellw4 + q] = acc[r];
      }
    }
  }
  // prefetch x chunk 1 (in flight across the barrier)
  xpA = ((const float4*)(x + ((size_t)(CH+ttA)*NB + b)*NI))[k4];
  xpB = ((const float4*)(x + ((size_t)(CH+ttB)*NB + b)*NI))[k4];
  barrier_lds();

  float hlast = 0.f;

#pragma unroll 1
  for (int ck = 0; ck < NCHUNK; ++ck){
    // ---- boundary: stage xs(ck+1) from prefetched regs ----
    if (ck + 1 < NCHUNK){
      union { _Float16 h[4]; uint2 u2; } pa, pb;
      pa.h[0]=(_Float16)xpA.x; pa.h[1]=(_Float16)xpA.y;
      pa.h[2]=(_Float16)xpA.z; pa.h[3]=(_Float16)xpA.w;
      *(uint2*)&xs[ttA][4*k4] = pa.u2;
      pb.h[0]=(_Float16)xpB.x; pb.h[1]=(_Float16)xpB.y;
      pb.h[2]=(_Float16)xpB.z; pb.h[3]=(_Float16)xpB.w;
      *(uint2*)&xs[ttB][4*k4] = pb.u2;
    }
    barrier_lds();
    if (ck + 2 < NCHUNK){
      const size_t t2 = (size_t)(ck + 2)*CH;
      xpA = ((const float4*)(x + ((t2 + ttA)*NB + b)*NI))[k4];
      xpB = ((const float4*)(x + ((t2 + ttB)*NB + b)*NI))[k4];
    }

    float (*xgc)[XGS] = xgp[ck & 1];
    float (*xgn)[XGS] = xgp[(ck + 1) & 1];
    const int tbase = ck*CH;
    const int ckh = ck;                      // head chunk handle (ckh-1)

    // ---------- 32 recurrent steps with interleaved slices ----------
#pragma unroll 4
    for (int tt = 0; tt < CH; ++tt){
      f32x4 sgv = *(const f32x4*)&xgc[tt][cellw4];
      const _Float16* hprev = &hist[(tbase + tt + 63) & 63][0];
      f16x8 afr0 = *(const f16x8*)&hprev[0*32 + quad*8];
      f16x8 afr1 = *(const f16x8*)&hprev[1*32 + quad*8];
      f16x8 afr2 = *(const f16x8*)&hprev[2*32 + quad*8];
      f16x8 afr3 = *(const f16x8*)&hprev[3*32 + quad*8];
      float gate[4];
#pragma unroll
      for (int q = 0; q < 4; ++q){
        f32x4 aA; aA[0] = sgv[q];
        aA = __builtin_amdgcn_mfma_f32_16x16x32_f16(afr0, whh[q][0], aA, 0, 0, 0);
        aA = __builtin_amdgcn_mfma_f32_16x16x32_f16(afr1, whh[q][1], aA, 0, 0, 0);
        f32x4 aB; aB[0] = 0.f;
        aB = __builtin_amdgcn_mfma_f32_16x16x32_f16(afr2, whh[q][2], aB, 0, 0, 0);
        aB = __builtin_amdgcn_mfma_f32_16x16x32_f16(afr3, whh[q][3], aB, 0, 0, 0);
        gate[q] = aA[0] + aB[0];
      }

      // x-GEMM slice for chunk ck+1 (steps 0,4,...,28)
      if ((tt & 3) == 0 && ck + 1 < NCHUNK){
        const int s_ = tt >> 2;              // 0..7 ; q = s_>>1, mt = s_&1
        switch (s_ >> 1){
          case 0: X_SLICE(0); break;
          case 1: X_SLICE(1); break;
          case 2: X_SLICE(2); break;
          case 3: X_SLICE(3); break;
        }
      }
      // head slice for chunk ck-1 (steps 2,6,...,30)
      if ((tt & 3) == 2 && ck >= 1){
        const int s_ = (tt - 2) >> 2;        // 0..7 ; jj = s_>>2, q = s_&3
        const int qh = s_ & 3;
        if (s_ < 4) HEAD_SLICE(0, accH0, fj0);
        else        HEAD_SLICE(1, accH1, fj1);
      }

      if (l < 16){
        float iv = sigm(gate[0]);
        float fv = sigm(gate[1]);
        float gv = tanhx(gate[2]);
        float ov = sigm(gate[3]);
        cst = __builtin_fmaf(fv, cst, iv*gv);
        float hv = ov * tanhx(cst);
        hlast = hv;
        hist[(tbase + tt) & 63][w*16 + l] = (_Float16)hv;
      }
      barrier_lds();
    }
  }

  // ---------- epilogue: head for chunk 31 (hist rows 32..63, no barriers) ----------
  {
    const int ckh = NCHUNK;                  // (ckh-1) = 31
#pragma unroll
    for (int s_ = 0; s_ < 8; ++s_){
      const int qh = s_ & 3;
      if (s_ < 4) HEAD_SLICE(0, accH0, fj0);
      else        HEAD_SLICE(1, accH1, fj1);
    }
  }

  // ---------- final hT / cT (from registers) ----------
  if (l < 16){
    hT[(size_t)b*NH + w*16 + l] = hlast;
    cT[(size_t)b*NH + w*16 + l] = cst;
  }
}

extern "C" void kernel_launch(void* const* d_in, const int* in_sizes, int n_in,
                              void* d_out, int out_size, void* d_ws, size_t ws_size,
                              hipStream_t stream) {
  (void)in_sizes; (void)n_in; (void)d_ws; (void)ws_size; (void)out_size;
  const float* x   = (const float*)d_in[0];
  const float* h0  = (const float*)d_in[1];
  const float* c0  = (const float*)d_in[2];
  const float* Wih = (const float*)d_in[3];
  const float* Whh = (const float*)d_in[4];
  const float* bih = (const float*)d_in[5];
  const float* bhh = (const float*)d_in[6];
  const float* fcW = (const float*)d_in[7];
  const float* fcb = (const float*)d_in[8];
  float* out = (float*)d_out;
  float* hT  = out + (size_t)TSTEPS*NB*NC;   // 4,718,592
  float* cT  = hT + (size_t)NB*NH;           // +32,768
  hipLaunchKernelGGL(lstm_mfma, dim3(NB), dim3(512), 0, stream,
                     x, h0, c0, Wih, Whh, bih, bhh, fcW, fcb, out, hT, cT);
}